// Round 7
// baseline (200.882 us; speedup 1.0000x reference)
//
#include <hip/hip_runtime.h>

// ResidualGNNLayer: h = x@W; gcn_norm gather-aggregate (CSR built per-call);
// +bias; LayerNorm; 0.5*h+0.5*x; relu.  N=100000, E=300000, D=256.
//
// ws layout:
//   h     : N*256 bf16 (shorts)          51.2 MB
//   dv    : N floats  (deg -> dinv)       0.4 MB
//   cnt   : N ints    (in-degree)         0.4 MB
//   off   : N ints    (CSR offsets)       0.4 MB
//   cur   : N ints    (placement cursor)  0.4 MB
//   bsum  : 512 ints
//   elist : E int2    {src, coef}         2.4 MB
//   Wf    : 65536 shorts (fragment-major bf16 W)  128 KB

#define NN 100000
#define NE 300000
#define DD 256
#define NB 391    // ceil(NN/256)
#define GMB 6250  // ceil(NN/16)

typedef __attribute__((ext_vector_type(8))) short short8;
typedef __attribute__((ext_vector_type(4))) float f32x4;
typedef __attribute__((ext_vector_type(4))) unsigned short u16x4;

static __device__ __forceinline__ short f2bf(float f) {
  union { float f; unsigned u; } a; a.f = f;
  unsigned r = a.u + 0x7fffu + ((a.u >> 16) & 1u);
  return (short)(r >> 16);
}

static __device__ __forceinline__ float bf2f(short s) {
  return __uint_as_float((unsigned)(unsigned short)s << 16);
}

__global__ __launch_bounds__(256) void k_init(float* __restrict__ dv,
                                              int* __restrict__ cnt) {
  int i = blockIdx.x * 256 + threadIdx.x;
  if (i < NN) { dv[i] = 0.0f; cnt[i] = 0; }
}

__global__ __launch_bounds__(256) void k_hist(const int* __restrict__ ei,
                                              const float* __restrict__ ew,
                                              float* __restrict__ dv,
                                              int* __restrict__ cnt) {
  int e = blockIdx.x * 256 + threadIdx.x;
  if (e < NE) {
    int d = ei[NE + e];
    atomicAdd(&dv[d], ew[e]);
    atomicAdd(&cnt[d], 1);
  }
}

__global__ __launch_bounds__(256) void k_dinv(float* __restrict__ dv) {
  int i = blockIdx.x * 256 + threadIdx.x;
  if (i < NN) dv[i] = rsqrtf(dv[i] + 1.0f);
}

__global__ __launch_bounds__(256) void k_scan1(const int* __restrict__ cnt,
                                               int* __restrict__ off,
                                               int* __restrict__ bsum) {
  __shared__ int tmp[256];
  int t = threadIdx.x;
  int i = blockIdx.x * 256 + t;
  int v = (i < NN) ? cnt[i] : 0;
  tmp[t] = v;
  __syncthreads();
  for (int o = 1; o < 256; o <<= 1) {
    int u = (t >= o) ? tmp[t - o] : 0;
    __syncthreads();
    tmp[t] += u;
    __syncthreads();
  }
  if (i < NN) off[i] = tmp[t] - v;
  if (t == 255) bsum[blockIdx.x] = tmp[t];
}

__global__ __launch_bounds__(512) void k_scan2(int* __restrict__ bsum) {
  __shared__ int tmp[512];
  int t = threadIdx.x;
  int v = (t < NB) ? bsum[t] : 0;
  tmp[t] = v;
  __syncthreads();
  for (int o = 1; o < 512; o <<= 1) {
    int u = (t >= o) ? tmp[t - o] : 0;
    __syncthreads();
    tmp[t] += u;
    __syncthreads();
  }
  bsum[t] = tmp[t] - v;
}

__global__ __launch_bounds__(256) void k_scan3(int* __restrict__ off,
                                               const int* __restrict__ bsum,
                                               int* __restrict__ cur) {
  int i = blockIdx.x * 256 + threadIdx.x;
  if (i < NN) {
    int o = off[i] + bsum[i >> 8];
    off[i] = o;
    cur[i] = o;
  }
}

__global__ __launch_bounds__(256) void k_place(const int* __restrict__ ei,
                                               const float* __restrict__ ew,
                                               const float* __restrict__ dv,
                                               int* __restrict__ cur,
                                               int2* __restrict__ elist) {
  int e = blockIdx.x * 256 + threadIdx.x;
  if (e >= NE) return;
  int s = ei[e];
  int d = ei[NE + e];
  float c = dv[s] * ew[e] * dv[d];
  int pos = atomicAdd(&cur[d], 1);
  elist[pos] = make_int2(s, __float_as_int(c));
}

// Pre-pack W (f32 [k][c]) into fragment-major bf16 Wf:
// short index = ((k>>5)*16 + (c>>4))*512 + ((c&15) + ((k>>3)&3)*16)*8 + (k&7)
__global__ __launch_bounds__(256) void k_wprep(const float* __restrict__ W,
                                               short* __restrict__ Wf) {
  int idx = blockIdx.x * 256 + threadIdx.x;  // 16384 total
  int k = idx >> 6;
  int c4 = idx & 63;
  const float4 v = *(const float4*)(W + k * 256 + c4 * 4);
  float vv[4] = {v.x, v.y, v.z, v.w};
#pragma unroll
  for (int i = 0; i < 4; ++i) {
    int c = c4 * 4 + i;
    int di = ((k >> 5) * 16 + (c >> 4)) * 512 + ((c & 15) + ((k >> 3) & 3) * 16) * 8 + (k & 7);
    Wf[di] = f2bf(vv[i]);
  }
}

// h = bf16(x @ W). NO LDS, NO BARRIERS. Block = 256 thr = 4 waves; block
// covers 16 node-rows x 256 W-cols; wave w = 64-col strip. Operand-swapped
// MFMA: A = W fragment (Wf, L2-resident), B = x fragment loaded DIRECTLY
// from global (lane's 8 contiguous f32 of its row) -> 16 independent
// float4 loads per thread, streaming like k_agg.
__global__ __launch_bounds__(256) void k_gemm(const float* __restrict__ x,
                                              const short* __restrict__ Wf,
                                              short* __restrict__ h) {
  const int t = threadIdx.x;
  const int lane = t & 63;
  const int wstrip = t >> 6;          // 64-col strip 0..3
  const int row0 = blockIdx.x * 16;

  int r = row0 + (lane & 15);
  int rc = (r < NN) ? r : (NN - 1);   // clamp; OOB discarded at store
  const float* rp = x + (size_t)rc * 256 + (lane >> 4) * 8;

  // ---- issue all 16 independent x loads (full K range of this lane's row)
  float4 fa[8], fb[8];
#pragma unroll
  for (int ks = 0; ks < 8; ++ks) {
    fa[ks] = *(const float4*)(rp + ks * 32);
    fb[ks] = *(const float4*)(rp + ks * 32 + 4);
  }

  f32x4 acc[4];
#pragma unroll
  for (int mc = 0; mc < 4; ++mc) acc[mc] = (f32x4)0.0f;

  const short* wbase = Wf + (size_t)(wstrip * 4) * 512 + lane * 8;

#pragma unroll
  for (int ks = 0; ks < 8; ++ks) {
    short8 bx;
    bx[0] = f2bf(fa[ks].x); bx[1] = f2bf(fa[ks].y);
    bx[2] = f2bf(fa[ks].z); bx[3] = f2bf(fa[ks].w);
    bx[4] = f2bf(fb[ks].x); bx[5] = f2bf(fb[ks].y);
    bx[6] = f2bf(fb[ks].z); bx[7] = f2bf(fb[ks].w);
    short8 aw[4];
#pragma unroll
    for (int mc = 0; mc < 4; ++mc)
      aw[mc] = *(const short8*)(wbase + (size_t)(ks * 16 + mc) * 512);
#pragma unroll
    for (int mc = 0; mc < 4; ++mc)
      acc[mc] = __builtin_amdgcn_mfma_f32_16x16x32_bf16(aw[mc], bx, acc[mc], 0, 0, 0);
  }

  // ---- epilogue: D[row = W-col][col = node-row]; lane packs 4 consecutive
  // W-cols of node-row (lane&15) -> one 8B store per mc.
  if (r < NN) {
#pragma unroll
    for (int mc = 0; mc < 4; ++mc) {
      int cbase = wstrip * 64 + mc * 16 + 4 * (lane >> 4);
      u16x4 s;
      s[0] = (unsigned short)f2bf(acc[mc][0]);
      s[1] = (unsigned short)f2bf(acc[mc][1]);
      s[2] = (unsigned short)f2bf(acc[mc][2]);
      s[3] = (unsigned short)f2bf(acc[mc][3]);
      *(u16x4*)(h + (size_t)r * 256 + cbase) = s;
    }
  }
}

// gather-aggregate + self-loop + bias + LayerNorm + residual + relu.
// One node per 32-lane half-wave; edge loop unrolled by 4.
__global__ __launch_bounds__(256) void k_agg(const short* __restrict__ h,
                                             const float* __restrict__ dv,
                                             const int* __restrict__ cnt,
                                             const int* __restrict__ off,
                                             const int2* __restrict__ elist,
                                             const float* __restrict__ x,
                                             const float* __restrict__ b,
                                             const float* __restrict__ gamma,
                                             const float* __restrict__ beta,
                                             float* __restrict__ out) {
  int node = (blockIdx.x * 256 + threadIdx.x) >> 5;
  if (node >= NN) return;
  int q = threadIdx.x & 31;           // sublane: features q*8 .. q*8+7

  const float di = dv[node];
  const float d2 = di * di;
  short8 hv = *(const short8*)(h + (size_t)node * 256 + q * 8);
  float a[8];
#pragma unroll
  for (int i = 0; i < 8; ++i) a[i] = bf2f(hv[i]) * d2;

  const int n = cnt[node];
  const int st = off[node];
  int j = 0;
  for (; j + 4 <= n; j += 4) {
    int2 r0 = elist[st + j];
    int2 r1 = elist[st + j + 1];
    int2 r2 = elist[st + j + 2];
    int2 r3 = elist[st + j + 3];
    short8 g0 = *(const short8*)(h + (size_t)r0.x * 256 + q * 8);
    short8 g1 = *(const short8*)(h + (size_t)r1.x * 256 + q * 8);
    short8 g2 = *(const short8*)(h + (size_t)r2.x * 256 + q * 8);
    short8 g3 = *(const short8*)(h + (size_t)r3.x * 256 + q * 8);
    float c0 = __int_as_float(r0.y);
    float c1 = __int_as_float(r1.y);
    float c2 = __int_as_float(r2.y);
    float c3 = __int_as_float(r3.y);
#pragma unroll
    for (int i = 0; i < 8; ++i)
      a[i] += c0 * bf2f(g0[i]) + c1 * bf2f(g1[i]) + c2 * bf2f(g2[i]) + c3 * bf2f(g3[i]);
  }
  for (; j < n; ++j) {
    int2 r0 = elist[st + j];
    short8 g0 = *(const short8*)(h + (size_t)r0.x * 256 + q * 8);
    float c0 = __int_as_float(r0.y);
#pragma unroll
    for (int i = 0; i < 8; ++i) a[i] += c0 * bf2f(g0[i]);
  }

  const float4 b0 = *(const float4*)(b + q * 8);
  const float4 b1 = *(const float4*)(b + q * 8 + 4);
  a[0] += b0.x; a[1] += b0.y; a[2] += b0.z; a[3] += b0.w;
  a[4] += b1.x; a[5] += b1.y; a[6] += b1.z; a[7] += b1.w;

  float s = 0.f, ss = 0.f;
#pragma unroll
  for (int i = 0; i < 8; ++i) { s += a[i]; ss += a[i] * a[i]; }
#pragma unroll
  for (int o = 16; o > 0; o >>= 1) {
    s += __shfl_xor(s, o);
    ss += __shfl_xor(ss, o);
  }
  const float mu = s * (1.0f / 256.0f);
  const float var = ss * (1.0f / 256.0f) - mu * mu;
  const float inv = rsqrtf(var + 1e-5f);

  const float4 g0 = *(const float4*)(gamma + q * 8);
  const float4 g1 = *(const float4*)(gamma + q * 8 + 4);
  const float4 e0 = *(const float4*)(beta + q * 8);
  const float4 e1 = *(const float4*)(beta + q * 8 + 4);
  const float4 x0 = *(const float4*)(x + (size_t)node * 256 + q * 8);
  const float4 x1 = *(const float4*)(x + (size_t)node * 256 + q * 8 + 4);

  float4 r0, r1;
  r0.x = fmaxf(0.5f * ((a[0] - mu) * inv * g0.x + e0.x) + 0.5f * x0.x, 0.f);
  r0.y = fmaxf(0.5f * ((a[1] - mu) * inv * g0.y + e0.y) + 0.5f * x0.y, 0.f);
  r0.z = fmaxf(0.5f * ((a[2] - mu) * inv * g0.z + e0.z) + 0.5f * x0.z, 0.f);
  r0.w = fmaxf(0.5f * ((a[3] - mu) * inv * g0.w + e0.w) + 0.5f * x0.w, 0.f);
  r1.x = fmaxf(0.5f * ((a[4] - mu) * inv * g1.x + e1.x) + 0.5f * x1.x, 0.f);
  r1.y = fmaxf(0.5f * ((a[5] - mu) * inv * g1.y + e1.y) + 0.5f * x1.y, 0.f);
  r1.z = fmaxf(0.5f * ((a[6] - mu) * inv * g1.z + e1.z) + 0.5f * x1.z, 0.f);
  r1.w = fmaxf(0.5f * ((a[7] - mu) * inv * g1.w + e1.w) + 0.5f * x1.w, 0.f);

  float* o = out + (size_t)node * 256 + q * 8;
  *(float4*)(o) = r0;
  *(float4*)(o + 4) = r1;
}

extern "C" void kernel_launch(void* const* d_in, const int* in_sizes, int n_in,
                              void* d_out, int out_size, void* d_ws, size_t ws_size,
                              hipStream_t stream) {
  const float* x     = (const float*)d_in[0];
  const int*   ei    = (const int*)d_in[1];
  const float* ew    = (const float*)d_in[2];
  const float* W     = (const float*)d_in[3];
  const float* b     = (const float*)d_in[4];
  const float* gamma = (const float*)d_in[5];
  const float* beta  = (const float*)d_in[6];
  float* out = (float*)d_out;

  short* h   = (short*)d_ws;                       // N*256 bf16
  float* dv  = (float*)(h + (size_t)NN * DD);      // N floats
  int*   cnt = (int*)(dv + NN);                    // N ints
  int*   off = cnt + NN;                           // N ints
  int*   cur = off + NN;                           // N ints
  int*   bsum = cur + NN;                          // 512 ints
  int2*  elist = (int2*)(bsum + 512);              // NE int2
  short* Wf  = (short*)(elist + NE);               // 65536 shorts

  k_init<<<NB, 256, 0, stream>>>(dv, cnt);
  k_hist<<<(NE + 255) / 256, 256, 0, stream>>>(ei, ew, dv, cnt);
  k_dinv<<<NB, 256, 0, stream>>>(dv);
  k_scan1<<<NB, 256, 0, stream>>>(cnt, off, bsum);
  k_scan2<<<1, 512, 0, stream>>>(bsum);
  k_scan3<<<NB, 256, 0, stream>>>(off, bsum, cur);
  k_place<<<(NE + 255) / 256, 256, 0, stream>>>(ei, ew, dv, cur, elist);

  k_wprep<<<64, 256, 0, stream>>>(W, Wf);
  k_gemm<<<GMB, 256, 0, stream>>>(x, Wf, h);

  k_agg<<<(NN * 32 + 255) / 256, 256, 0, stream>>>(h, dv, cnt, off, elist, x, b, gamma, beta, out);
}

// Round 8
// 167.077 us; speedup vs baseline: 1.2023x; 1.2023x over previous
//
#include <hip/hip_runtime.h>

// ResidualGNNLayer: h = x@W; gcn_norm gather-aggregate (CSR built per-call);
// +bias; LayerNorm; 0.5*h+0.5*x; relu.  N=100000, E=300000, D=256.
//
// ws layout:
//   h     : N*256 bf16 (shorts)          51.2 MB
//   dv    : N floats  (deg -> dinv)       0.4 MB
//   cnt   : N ints    (in-degree)         0.4 MB
//   off   : N ints    (CSR offsets)       0.4 MB
//   cur   : N ints    (placement cursor)  0.4 MB
//   bsum  : 512 ints
//   elist : E int2    {src, coef}         2.4 MB
//   Wf    : 65536 shorts (fragment-major bf16 W)  128 KB

#define NN 100000
#define NE 300000
#define DD 256
#define NB 391    // ceil(NN/256)
#define GMB 3125  // NN/32 exact

typedef __attribute__((ext_vector_type(8))) short short8;
typedef __attribute__((ext_vector_type(4))) float f32x4;
typedef __attribute__((ext_vector_type(4))) unsigned short u16x4;

static __device__ __forceinline__ short f2bf(float f) {
  union { float f; unsigned u; } a; a.f = f;
  unsigned r = a.u + 0x7fffu + ((a.u >> 16) & 1u);
  return (short)(r >> 16);
}

static __device__ __forceinline__ float bf2f(short s) {
  return __uint_as_float((unsigned)(unsigned short)s << 16);
}

// packed f32x2 -> bf16x2 (RNE), single VOP3 instruction
static __device__ __forceinline__ unsigned cvtpk(float a, float b) {
  unsigned r;
  asm("v_cvt_pk_bf16_f32 %0, %1, %2" : "=v"(r) : "v"(a), "v"(b));
  return r;
}

// async global->LDS, 16 bytes per lane (dest = uniform base + lane*16)
static __device__ __forceinline__ void gld16(const float* g, void* l) {
  __builtin_amdgcn_global_load_lds(
      (const __attribute__((address_space(1))) unsigned int*)g,
      (__attribute__((address_space(3))) unsigned int*)l, 16, 0, 0);
}

__global__ __launch_bounds__(256) void k_init(float* __restrict__ dv,
                                              int* __restrict__ cnt) {
  int i = blockIdx.x * 256 + threadIdx.x;
  if (i < NN) { dv[i] = 0.0f; cnt[i] = 0; }
}

__global__ __launch_bounds__(256) void k_hist(const int* __restrict__ ei,
                                              const float* __restrict__ ew,
                                              float* __restrict__ dv,
                                              int* __restrict__ cnt) {
  int e = blockIdx.x * 256 + threadIdx.x;
  if (e < NE) {
    int d = ei[NE + e];
    atomicAdd(&dv[d], ew[e]);
    atomicAdd(&cnt[d], 1);
  }
}

__global__ __launch_bounds__(256) void k_scan1(const int* __restrict__ cnt,
                                               int* __restrict__ off,
                                               int* __restrict__ bsum) {
  __shared__ int tmp[256];
  int t = threadIdx.x;
  int i = blockIdx.x * 256 + t;
  int v = (i < NN) ? cnt[i] : 0;
  tmp[t] = v;
  __syncthreads();
  for (int o = 1; o < 256; o <<= 1) {
    int u = (t >= o) ? tmp[t - o] : 0;
    __syncthreads();
    tmp[t] += u;
    __syncthreads();
  }
  if (i < NN) off[i] = tmp[t] - v;
  if (t == 255) bsum[blockIdx.x] = tmp[t];
}

__global__ __launch_bounds__(512) void k_scan2(int* __restrict__ bsum) {
  __shared__ int tmp[512];
  int t = threadIdx.x;
  int v = (t < NB) ? bsum[t] : 0;
  tmp[t] = v;
  __syncthreads();
  for (int o = 1; o < 512; o <<= 1) {
    int u = (t >= o) ? tmp[t - o] : 0;
    __syncthreads();
    tmp[t] += u;
    __syncthreads();
  }
  bsum[t] = tmp[t] - v;
}

// also finalizes dv = rsqrt(deg+1)  (k_dinv folded in)
__global__ __launch_bounds__(256) void k_scan3(int* __restrict__ off,
                                               const int* __restrict__ bsum,
                                               int* __restrict__ cur,
                                               float* __restrict__ dv) {
  int i = blockIdx.x * 256 + threadIdx.x;
  if (i < NN) {
    int o = off[i] + bsum[i >> 8];
    off[i] = o;
    cur[i] = o;
    dv[i] = rsqrtf(dv[i] + 1.0f);
  }
}

__global__ __launch_bounds__(256) void k_place(const int* __restrict__ ei,
                                               const float* __restrict__ ew,
                                               const float* __restrict__ dv,
                                               int* __restrict__ cur,
                                               int2* __restrict__ elist) {
  int e = blockIdx.x * 256 + threadIdx.x;
  if (e >= NE) return;
  int s = ei[e];
  int d = ei[NE + e];
  float c = dv[s] * ew[e] * dv[d];
  int pos = atomicAdd(&cur[d], 1);
  elist[pos] = make_int2(s, __float_as_int(c));
}

// Pre-pack W (f32 [k][c]) into fragment-major bf16 Wf:
// short index = ((k>>5)*16 + (c>>4))*512 + ((c&15) + ((k>>3)&3)*16)*8 + (k&7)
__global__ __launch_bounds__(256) void k_wprep(const float* __restrict__ W,
                                               short* __restrict__ Wf) {
  int idx = blockIdx.x * 256 + threadIdx.x;  // 16384 total
  int k = idx >> 6;
  int c4 = idx & 63;
  const float4 v = *(const float4*)(W + k * 256 + c4 * 4);
  float vv[4] = {v.x, v.y, v.z, v.w};
#pragma unroll
  for (int i = 0; i < 4; ++i) {
    int c = c4 * 4 + i;
    int di = ((k >> 5) * 16 + (c >> 4)) * 512 + ((c & 15) + ((k >> 3) & 3) * 16) * 8 + (k & 7);
    Wf[di] = f2bf(vv[i]);
  }
}

// h = bf16(x @ W). BM=32, BN=256 (full), full K=256 staged via
// global_load_lds into 32 KB f32 LDS (linear dest, XOR-swizzled SOURCE,
// same XOR on read -- rule: both-sides-or-neither). One barrier. 4 waves,
// wave = 64-col strip x all 32 rows. Operand-swapped MFMA (A = W frag from
// Wf/L2, B = x frag from LDS, cvt_pk f32->bf16 on read).
__global__ __launch_bounds__(256) void k_gemm(const float* __restrict__ x,
                                              const short* __restrict__ Wf,
                                              short* __restrict__ h) {
  __shared__ float As[32 * 256];  // 32 KB; row stride 1024B; 64 chunks/row

  const int t = threadIdx.x;
  const int lane = t & 63;
  const int wid = t >> 6;            // wave 0..3 = 64-col strip
  const int row0 = blockIdx.x * 32;  // NN = 3125*32 exactly

  // ---- stage: 2048 chunks of 16B; issue i stages tile-row r = i*4+wid,
  // lane stages LDS chunk `lane` of that row from global chunk lane^(r&7).
#pragma unroll
  for (int i = 0; i < 8; ++i) {
    const int r = i * 4 + wid;
    const float* src = x + (size_t)(row0 + r) * 256 + ((lane ^ (r & 7)) << 2);
    gld16(src, (char*)As + (r << 10));  // uniform base; +lane*16 implicit
  }
  __syncthreads();

  f32x4 acc[4][2];
#pragma unroll
  for (int mc = 0; mc < 4; ++mc)
#pragma unroll
    for (int nr = 0; nr < 2; ++nr) acc[mc][nr] = (f32x4)0.0f;

  const short* wbase = Wf + (size_t)(wid * 4) * 512 + lane * 8;

#pragma unroll
  for (int ks = 0; ks < 8; ++ks) {
    // B operand (x rows) from LDS: row r = nr*16 + (lane&15),
    // logical f32 chunks c, c+1 where c = ks*8 + (lane>>4)*2
    short8 bx[2];
#pragma unroll
    for (int nr = 0; nr < 2; ++nr) {
      const int r = nr * 16 + (lane & 15);
      const int c = ks * 8 + (lane >> 4) * 2;
      const f32x4 lo = *(const f32x4*)((const char*)As + (r << 10) + ((c ^ (r & 7)) << 4));
      const f32x4 hi = *(const f32x4*)((const char*)As + (r << 10) + (((c + 1) ^ (r & 7)) << 4));
      union { short8 s; unsigned u[4]; } U;
      U.u[0] = cvtpk(lo[0], lo[1]);
      U.u[1] = cvtpk(lo[2], lo[3]);
      U.u[2] = cvtpk(hi[0], hi[1]);
      U.u[3] = cvtpk(hi[2], hi[3]);
      bx[nr] = U.s;
    }
    short8 aw[4];
#pragma unroll
    for (int mc = 0; mc < 4; ++mc)
      aw[mc] = *(const short8*)(wbase + (size_t)(ks * 16 + mc) * 512);
#pragma unroll
    for (int mc = 0; mc < 4; ++mc)
#pragma unroll
      for (int nr = 0; nr < 2; ++nr)
        acc[mc][nr] = __builtin_amdgcn_mfma_f32_16x16x32_bf16(
            aw[mc], bx[nr], acc[mc][nr], 0, 0, 0);
  }

  // ---- epilogue: D[row = W-col][col = node-row]; lane packs 4 consecutive
  // W-cols of node-row (lane&15) -> one 8B store per (mc, nr).
#pragma unroll
  for (int mc = 0; mc < 4; ++mc) {
    const int cbase = wid * 64 + mc * 16 + 4 * (lane >> 4);
#pragma unroll
    for (int nr = 0; nr < 2; ++nr) {
      const int r = row0 + nr * 16 + (lane & 15);
      u16x4 s;
      s[0] = (unsigned short)f2bf(acc[mc][nr][0]);
      s[1] = (unsigned short)f2bf(acc[mc][nr][1]);
      s[2] = (unsigned short)f2bf(acc[mc][nr][2]);
      s[3] = (unsigned short)f2bf(acc[mc][nr][3]);
      *(u16x4*)(h + (size_t)r * 256 + cbase) = s;
    }
  }
}

// gather-aggregate + self-loop + bias + LayerNorm + residual + relu.
// One node per 32-lane half-wave; edge loop unrolled by 4.
__global__ __launch_bounds__(256) void k_agg(const short* __restrict__ h,
                                             const float* __restrict__ dv,
                                             const int* __restrict__ cnt,
                                             const int* __restrict__ off,
                                             const int2* __restrict__ elist,
                                             const float* __restrict__ x,
                                             const float* __restrict__ b,
                                             const float* __restrict__ gamma,
                                             const float* __restrict__ beta,
                                             float* __restrict__ out) {
  int node = (blockIdx.x * 256 + threadIdx.x) >> 5;
  if (node >= NN) return;
  int q = threadIdx.x & 31;           // sublane: features q*8 .. q*8+7

  const float di = dv[node];
  const float d2 = di * di;
  short8 hv = *(const short8*)(h + (size_t)node * 256 + q * 8);
  float a[8];
#pragma unroll
  for (int i = 0; i < 8; ++i) a[i] = bf2f(hv[i]) * d2;

  const int n = cnt[node];
  const int st = off[node];
  int j = 0;
  for (; j + 4 <= n; j += 4) {
    int2 r0 = elist[st + j];
    int2 r1 = elist[st + j + 1];
    int2 r2 = elist[st + j + 2];
    int2 r3 = elist[st + j + 3];
    short8 g0 = *(const short8*)(h + (size_t)r0.x * 256 + q * 8);
    short8 g1 = *(const short8*)(h + (size_t)r1.x * 256 + q * 8);
    short8 g2 = *(const short8*)(h + (size_t)r2.x * 256 + q * 8);
    short8 g3 = *(const short8*)(h + (size_t)r3.x * 256 + q * 8);
    float c0 = __int_as_float(r0.y);
    float c1 = __int_as_float(r1.y);
    float c2 = __int_as_float(r2.y);
    float c3 = __int_as_float(r3.y);
#pragma unroll
    for (int i = 0; i < 8; ++i)
      a[i] += c0 * bf2f(g0[i]) + c1 * bf2f(g1[i]) + c2 * bf2f(g2[i]) + c3 * bf2f(g3[i]);
  }
  for (; j < n; ++j) {
    int2 r0 = elist[st + j];
    short8 g0 = *(const short8*)(h + (size_t)r0.x * 256 + q * 8);
    float c0 = __int_as_float(r0.y);
#pragma unroll
    for (int i = 0; i < 8; ++i) a[i] += c0 * bf2f(g0[i]);
  }

  const float4 b0 = *(const float4*)(b + q * 8);
  const float4 b1 = *(const float4*)(b + q * 8 + 4);
  a[0] += b0.x; a[1] += b0.y; a[2] += b0.z; a[3] += b0.w;
  a[4] += b1.x; a[5] += b1.y; a[6] += b1.z; a[7] += b1.w;

  float s = 0.f, ss = 0.f;
#pragma unroll
  for (int i = 0; i < 8; ++i) { s += a[i]; ss += a[i] * a[i]; }
#pragma unroll
  for (int o = 16; o > 0; o >>= 1) {
    s += __shfl_xor(s, o);
    ss += __shfl_xor(ss, o);
  }
  const float mu = s * (1.0f / 256.0f);
  const float var = ss * (1.0f / 256.0f) - mu * mu;
  const float inv = rsqrtf(var + 1e-5f);

  const float4 g0 = *(const float4*)(gamma + q * 8);
  const float4 g1 = *(const float4*)(gamma + q * 8 + 4);
  const float4 e0 = *(const float4*)(beta + q * 8);
  const float4 e1 = *(const float4*)(beta + q * 8 + 4);
  const float4 x0 = *(const float4*)(x + (size_t)node * 256 + q * 8);
  const float4 x1 = *(const float4*)(x + (size_t)node * 256 + q * 8 + 4);

  float4 r0, r1;
  r0.x = fmaxf(0.5f * ((a[0] - mu) * inv * g0.x + e0.x) + 0.5f * x0.x, 0.f);
  r0.y = fmaxf(0.5f * ((a[1] - mu) * inv * g0.y + e0.y) + 0.5f * x0.y, 0.f);
  r0.z = fmaxf(0.5f * ((a[2] - mu) * inv * g0.z + e0.z) + 0.5f * x0.z, 0.f);
  r0.w = fmaxf(0.5f * ((a[3] - mu) * inv * g0.w + e0.w) + 0.5f * x0.w, 0.f);
  r1.x = fmaxf(0.5f * ((a[4] - mu) * inv * g1.x + e1.x) + 0.5f * x1.x, 0.f);
  r1.y = fmaxf(0.5f * ((a[5] - mu) * inv * g1.y + e1.y) + 0.5f * x1.y, 0.f);
  r1.z = fmaxf(0.5f * ((a[6] - mu) * inv * g1.z + e1.z) + 0.5f * x1.z, 0.f);
  r1.w = fmaxf(0.5f * ((a[7] - mu) * inv * g1.w + e1.w) + 0.5f * x1.w, 0.f);

  float* o = out + (size_t)node * 256 + q * 8;
  *(float4*)(o) = r0;
  *(float4*)(o + 4) = r1;
}

extern "C" void kernel_launch(void* const* d_in, const int* in_sizes, int n_in,
                              void* d_out, int out_size, void* d_ws, size_t ws_size,
                              hipStream_t stream) {
  const float* x     = (const float*)d_in[0];
  const int*   ei    = (const int*)d_in[1];
  const float* ew    = (const float*)d_in[2];
  const float* W     = (const float*)d_in[3];
  const float* b     = (const float*)d_in[4];
  const float* gamma = (const float*)d_in[5];
  const float* beta  = (const float*)d_in[6];
  float* out = (float*)d_out;

  short* h   = (short*)d_ws;                       // N*256 bf16
  float* dv  = (float*)(h + (size_t)NN * DD);      // N floats
  int*   cnt = (int*)(dv + NN);                    // N ints
  int*   off = cnt + NN;                           // N ints
  int*   cur = off + NN;                           // N ints
  int*   bsum = cur + NN;                          // 512 ints
  int2*  elist = (int2*)(bsum + 512);              // NE int2
  short* Wf  = (short*)(elist + NE);               // 65536 shorts

  k_init<<<NB, 256, 0, stream>>>(dv, cnt);
  k_hist<<<(NE + 255) / 256, 256, 0, stream>>>(ei, ew, dv, cnt);
  k_scan1<<<NB, 256, 0, stream>>>(cnt, off, bsum);
  k_scan2<<<1, 512, 0, stream>>>(bsum);
  k_scan3<<<NB, 256, 0, stream>>>(off, bsum, cur, dv);
  k_place<<<(NE + 255) / 256, 256, 0, stream>>>(ei, ew, dv, cur, elist);

  k_wprep<<<64, 256, 0, stream>>>(W, Wf);
  k_gemm<<<GMB, 256, 0, stream>>>(x, Wf, h);

  k_agg<<<(NN * 32 + 255) / 256, 256, 0, stream>>>(h, dv, cnt, off, elist, x, b, gamma, beta, out);
}

// Round 9
// 153.165 us; speedup vs baseline: 1.3115x; 1.0908x over previous
//
#include <hip/hip_runtime.h>

// ResidualGNNLayer: h = x@W; gcn_norm gather-aggregate (CSR built per-call);
// +bias; LayerNorm; 0.5*h+0.5*x; relu.  N=100000, E=300000, D=256.
//
// ws layout:
//   h     : N*256 bf16 (shorts)          51.2 MB
//   dv    : N floats  (deg -> dinv)       0.4 MB
//   cnt   : N ints    (in-degree)         0.4 MB
//   off   : N ints    (CSR offsets)       0.4 MB
//   cur   : N ints    (placement cursor)  0.4 MB
//   bsum  : 512 ints
//   elist : E int2    {src, coef}         2.4 MB
//   Wf    : 65536 shorts (fragment-major bf16 W)  128 KB

#define NN 100000
#define NE 300000
#define DD 256
#define NB 391    // ceil(NN/256)
#define GMB 625   // blocks; each does 5 tiles of 32 rows = 3125*32 = NN

typedef __attribute__((ext_vector_type(8))) short short8;
typedef __attribute__((ext_vector_type(4))) float f32x4;
typedef __attribute__((ext_vector_type(4))) unsigned short u16x4;

static __device__ __forceinline__ short f2bf(float f) {
  union { float f; unsigned u; } a; a.f = f;
  unsigned r = a.u + 0x7fffu + ((a.u >> 16) & 1u);
  return (short)(r >> 16);
}

static __device__ __forceinline__ float bf2f(short s) {
  return __uint_as_float((unsigned)(unsigned short)s << 16);
}

// packed f32x2 -> bf16x2 (RNE), single VOP3 instruction
static __device__ __forceinline__ unsigned cvtpk(float a, float b) {
  unsigned r;
  asm("v_cvt_pk_bf16_f32 %0, %1, %2" : "=v"(r) : "v"(a), "v"(b));
  return r;
}

// async global->LDS, 16 bytes per lane (dest = uniform base + lane*16)
static __device__ __forceinline__ void gld16(const float* g, void* l) {
  __builtin_amdgcn_global_load_lds(
      (const __attribute__((address_space(1))) unsigned int*)g,
      (__attribute__((address_space(3))) unsigned int*)l, 16, 0, 0);
}

__global__ __launch_bounds__(256) void k_init(float* __restrict__ dv,
                                              int* __restrict__ cnt) {
  int i = blockIdx.x * 256 + threadIdx.x;
  if (i < NN) { dv[i] = 0.0f; cnt[i] = 0; }
}

__global__ __launch_bounds__(256) void k_hist(const int* __restrict__ ei,
                                              const float* __restrict__ ew,
                                              float* __restrict__ dv,
                                              int* __restrict__ cnt) {
  int e = blockIdx.x * 256 + threadIdx.x;
  if (e < NE) {
    int d = ei[NE + e];
    atomicAdd(&dv[d], ew[e]);
    atomicAdd(&cnt[d], 1);
  }
}

__global__ __launch_bounds__(256) void k_scan1(const int* __restrict__ cnt,
                                               int* __restrict__ off,
                                               int* __restrict__ bsum) {
  __shared__ int tmp[256];
  int t = threadIdx.x;
  int i = blockIdx.x * 256 + t;
  int v = (i < NN) ? cnt[i] : 0;
  tmp[t] = v;
  __syncthreads();
  for (int o = 1; o < 256; o <<= 1) {
    int u = (t >= o) ? tmp[t - o] : 0;
    __syncthreads();
    tmp[t] += u;
    __syncthreads();
  }
  if (i < NN) off[i] = tmp[t] - v;
  if (t == 255) bsum[blockIdx.x] = tmp[t];
}

__global__ __launch_bounds__(512) void k_scan2(int* __restrict__ bsum) {
  __shared__ int tmp[512];
  int t = threadIdx.x;
  int v = (t < NB) ? bsum[t] : 0;
  tmp[t] = v;
  __syncthreads();
  for (int o = 1; o < 512; o <<= 1) {
    int u = (t >= o) ? tmp[t - o] : 0;
    __syncthreads();
    tmp[t] += u;
    __syncthreads();
  }
  bsum[t] = tmp[t] - v;
}

// also finalizes dv = rsqrt(deg+1)  (k_dinv folded in)
__global__ __launch_bounds__(256) void k_scan3(int* __restrict__ off,
                                               const int* __restrict__ bsum,
                                               int* __restrict__ cur,
                                               float* __restrict__ dv) {
  int i = blockIdx.x * 256 + threadIdx.x;
  if (i < NN) {
    int o = off[i] + bsum[i >> 8];
    off[i] = o;
    cur[i] = o;
    dv[i] = rsqrtf(dv[i] + 1.0f);
  }
}

__global__ __launch_bounds__(256) void k_place(const int* __restrict__ ei,
                                               const float* __restrict__ ew,
                                               const float* __restrict__ dv,
                                               int* __restrict__ cur,
                                               int2* __restrict__ elist) {
  int e = blockIdx.x * 256 + threadIdx.x;
  if (e >= NE) return;
  int s = ei[e];
  int d = ei[NE + e];
  float c = dv[s] * ew[e] * dv[d];
  int pos = atomicAdd(&cur[d], 1);
  elist[pos] = make_int2(s, __float_as_int(c));
}

// Pre-pack W (f32 [k][c]) into fragment-major bf16 Wf:
// short index = ((k>>5)*16 + (c>>4))*512 + ((c&15) + ((k>>3)&3)*16)*8 + (k&7)
__global__ __launch_bounds__(256) void k_wprep(const float* __restrict__ W,
                                               short* __restrict__ Wf) {
  int idx = blockIdx.x * 256 + threadIdx.x;  // 16384 total
  int k = idx >> 6;
  int c4 = idx & 63;
  const float4 v = *(const float4*)(W + k * 256 + c4 * 4);
  float vv[4] = {v.x, v.y, v.z, v.w};
#pragma unroll
  for (int i = 0; i < 4; ++i) {
    int c = c4 * 4 + i;
    int di = ((k >> 5) * 16 + (c >> 4)) * 512 + ((c & 15) + ((k >> 3) & 3) * 16) * 8 + (k & 7);
    Wf[di] = f2bf(vv[i]);
  }
}

// h = bf16(x @ W). 5-tile pipeline per block: BM=32, BN=256, full K=256.
// Double-buffered 2x32KB LDS, DMA staging (global_load_lds), counted
// vmcnt(8) waits (never 0 in steady state), raw s_barrier. All 32 W
// fragments hoisted to registers once per block. Operand-swapped MFMA.
__global__ __launch_bounds__(256, 2) void k_gemm(const float* __restrict__ x,
                                                 const short* __restrict__ Wf,
                                                 short* __restrict__ h) {
  __shared__ float As[2][32 * 256];  // 2 x 32 KB; row stride 1024B

  const int t = threadIdx.x;
  const int lane = t & 63;
  const int wid = t >> 6;            // wave 0..3 = 64-col strip
  const int tile0 = blockIdx.x * 5;

  // ---- hoist all W fragments for this wave's strip (32 x 16B = 128 VGPR)
  short8 aw[8][4];
  const short* wbase = Wf + (size_t)(wid * 4) * 512 + lane * 8;
#pragma unroll
  for (int ks = 0; ks < 8; ++ks)
#pragma unroll
    for (int mc = 0; mc < 4; ++mc)
      aw[ks][mc] = *(const short8*)(wbase + (size_t)(ks * 16 + mc) * 512);

  // stage tile T into buffer B: 8 DMA issues per thread, wave-uniform dest
#define STAGE(T, B)                                                          \
  _Pragma("unroll")                                                          \
  for (int i = 0; i < 8; ++i) {                                              \
    const int r_ = i * 4 + wid;                                              \
    const float* src_ = x + ((size_t)(tile0 + (T)) * 32 + r_) * 256 +        \
                        ((lane ^ (r_ & 7)) << 2);                            \
    gld16(src_, (char*)As[B] + (r_ << 10));                                  \
  }

  STAGE(0, 0);

#pragma unroll
  for (int tt = 0; tt < 5; ++tt) {
    const int cur = tt & 1;
    if (tt < 4) { STAGE(tt + 1, cur ^ 1); }

    // wait for tile tt's 8 DMAs (allow tile tt+1's 8 to stay in flight)
    asm volatile("s_waitcnt vmcnt(8)" ::: "memory");
    __builtin_amdgcn_s_barrier();
    __builtin_amdgcn_sched_barrier(0);

    f32x4 acc[4][2];
#pragma unroll
    for (int mc = 0; mc < 4; ++mc)
#pragma unroll
      for (int nr = 0; nr < 2; ++nr) acc[mc][nr] = (f32x4)0.0f;

#pragma unroll
    for (int ks = 0; ks < 8; ++ks) {
      short8 bx[2];
#pragma unroll
      for (int nr = 0; nr < 2; ++nr) {
        const int r = nr * 16 + (lane & 15);
        const int c = ks * 8 + (lane >> 4) * 2;
        const f32x4 lo = *(const f32x4*)((const char*)As[cur] + (r << 10) + ((c ^ (r & 7)) << 4));
        const f32x4 hi = *(const f32x4*)((const char*)As[cur] + (r << 10) + (((c + 1) ^ (r & 7)) << 4));
        union { short8 s; unsigned u[4]; } U;
        U.u[0] = cvtpk(lo[0], lo[1]);
        U.u[1] = cvtpk(lo[2], lo[3]);
        U.u[2] = cvtpk(hi[0], hi[1]);
        U.u[3] = cvtpk(hi[2], hi[3]);
        bx[nr] = U.s;
      }
#pragma unroll
      for (int mc = 0; mc < 4; ++mc)
#pragma unroll
        for (int nr = 0; nr < 2; ++nr)
          acc[mc][nr] = __builtin_amdgcn_mfma_f32_16x16x32_bf16(
              aw[ks][mc], bx[nr], acc[mc][nr], 0, 0, 0);
    }

    // all LDS reads for this tile are consumed; release the buffer
    __builtin_amdgcn_s_barrier();

    // epilogue: D[row=W-col][col=node-row]; 8B packed stores
    const int rowb = (tile0 + tt) * 32;
#pragma unroll
    for (int mc = 0; mc < 4; ++mc) {
      const int cbase = wid * 64 + mc * 16 + 4 * (lane >> 4);
#pragma unroll
      for (int nr = 0; nr < 2; ++nr) {
        const int r = rowb + nr * 16 + (lane & 15);
        u16x4 s;
        s[0] = (unsigned short)f2bf(acc[mc][nr][0]);
        s[1] = (unsigned short)f2bf(acc[mc][nr][1]);
        s[2] = (unsigned short)f2bf(acc[mc][nr][2]);
        s[3] = (unsigned short)f2bf(acc[mc][nr][3]);
        *(u16x4*)(h + (size_t)r * 256 + cbase) = s;
      }
    }
  }
#undef STAGE
}

// gather-aggregate + self-loop + bias + LayerNorm + residual + relu.
// One node per 32-lane half-wave; edge loop unrolled by 4.
__global__ __launch_bounds__(256) void k_agg(const short* __restrict__ h,
                                             const float* __restrict__ dv,
                                             const int* __restrict__ cnt,
                                             const int* __restrict__ off,
                                             const int2* __restrict__ elist,
                                             const float* __restrict__ x,
                                             const float* __restrict__ b,
                                             const float* __restrict__ gamma,
                                             const float* __restrict__ beta,
                                             float* __restrict__ out) {
  int node = (blockIdx.x * 256 + threadIdx.x) >> 5;
  if (node >= NN) return;
  int q = threadIdx.x & 31;           // sublane: features q*8 .. q*8+7

  const float di = dv[node];
  const float d2 = di * di;
  short8 hv = *(const short8*)(h + (size_t)node * 256 + q * 8);
  float a[8];
#pragma unroll
  for (int i = 0; i < 8; ++i) a[i] = bf2f(hv[i]) * d2;

  const int n = cnt[node];
  const int st = off[node];
  int j = 0;
  for (; j + 4 <= n; j += 4) {
    int2 r0 = elist[st + j];
    int2 r1 = elist[st + j + 1];
    int2 r2 = elist[st + j + 2];
    int2 r3 = elist[st + j + 3];
    short8 g0 = *(const short8*)(h + (size_t)r0.x * 256 + q * 8);
    short8 g1 = *(const short8*)(h + (size_t)r1.x * 256 + q * 8);
    short8 g2 = *(const short8*)(h + (size_t)r2.x * 256 + q * 8);
    short8 g3 = *(const short8*)(h + (size_t)r3.x * 256 + q * 8);
    float c0 = __int_as_float(r0.y);
    float c1 = __int_as_float(r1.y);
    float c2 = __int_as_float(r2.y);
    float c3 = __int_as_float(r3.y);
#pragma unroll
    for (int i = 0; i < 8; ++i)
      a[i] += c0 * bf2f(g0[i]) + c1 * bf2f(g1[i]) + c2 * bf2f(g2[i]) + c3 * bf2f(g3[i]);
  }
  for (; j < n; ++j) {
    int2 r0 = elist[st + j];
    short8 g0 = *(const short8*)(h + (size_t)r0.x * 256 + q * 8);
    float c0 = __int_as_float(r0.y);
#pragma unroll
    for (int i = 0; i < 8; ++i) a[i] += c0 * bf2f(g0[i]);
  }

  const float4 b0 = *(const float4*)(b + q * 8);
  const float4 b1 = *(const float4*)(b + q * 8 + 4);
  a[0] += b0.x; a[1] += b0.y; a[2] += b0.z; a[3] += b0.w;
  a[4] += b1.x; a[5] += b1.y; a[6] += b1.z; a[7] += b1.w;

  float s = 0.f, ss = 0.f;
#pragma unroll
  for (int i = 0; i < 8; ++i) { s += a[i]; ss += a[i] * a[i]; }
#pragma unroll
  for (int o = 16; o > 0; o >>= 1) {
    s += __shfl_xor(s, o);
    ss += __shfl_xor(ss, o);
  }
  const float mu = s * (1.0f / 256.0f);
  const float var = ss * (1.0f / 256.0f) - mu * mu;
  const float inv = rsqrtf(var + 1e-5f);

  const float4 g0 = *(const float4*)(gamma + q * 8);
  const float4 g1 = *(const float4*)(gamma + q * 8 + 4);
  const float4 e0 = *(const float4*)(beta + q * 8);
  const float4 e1 = *(const float4*)(beta + q * 8 + 4);
  const float4 x0 = *(const float4*)(x + (size_t)node * 256 + q * 8);
  const float4 x1 = *(const float4*)(x + (size_t)node * 256 + q * 8 + 4);

  float4 r0, r1;
  r0.x = fmaxf(0.5f * ((a[0] - mu) * inv * g0.x + e0.x) + 0.5f * x0.x, 0.f);
  r0.y = fmaxf(0.5f * ((a[1] - mu) * inv * g0.y + e0.y) + 0.5f * x0.y, 0.f);
  r0.z = fmaxf(0.5f * ((a[2] - mu) * inv * g0.z + e0.z) + 0.5f * x0.z, 0.f);
  r0.w = fmaxf(0.5f * ((a[3] - mu) * inv * g0.w + e0.w) + 0.5f * x0.w, 0.f);
  r1.x = fmaxf(0.5f * ((a[4] - mu) * inv * g1.x + e1.x) + 0.5f * x1.x, 0.f);
  r1.y = fmaxf(0.5f * ((a[5] - mu) * inv * g1.y + e1.y) + 0.5f * x1.y, 0.f);
  r1.z = fmaxf(0.5f * ((a[6] - mu) * inv * g1.z + e1.z) + 0.5f * x1.z, 0.f);
  r1.w = fmaxf(0.5f * ((a[7] - mu) * inv * g1.w + e1.w) + 0.5f * x1.w, 0.f);

  float* o = out + (size_t)node * 256 + q * 8;
  *(float4*)(o) = r0;
  *(float4*)(o + 4) = r1;
}

extern "C" void kernel_launch(void* const* d_in, const int* in_sizes, int n_in,
                              void* d_out, int out_size, void* d_ws, size_t ws_size,
                              hipStream_t stream) {
  const float* x     = (const float*)d_in[0];
  const int*   ei    = (const int*)d_in[1];
  const float* ew    = (const float*)d_in[2];
  const float* W     = (const float*)d_in[3];
  const float* b     = (const float*)d_in[4];
  const float* gamma = (const float*)d_in[5];
  const float* beta  = (const float*)d_in[6];
  float* out = (float*)d_out;

  short* h   = (short*)d_ws;                       // N*256 bf16
  float* dv  = (float*)(h + (size_t)NN * DD);      // N floats
  int*   cnt = (int*)(dv + NN);                    // N ints
  int*   off = cnt + NN;                           // N ints
  int*   cur = off + NN;                           // N ints
  int*   bsum = cur + NN;                          // 512 ints
  int2*  elist = (int2*)(bsum + 512);              // NE int2
  short* Wf  = (short*)(elist + NE);               // 65536 shorts

  k_init<<<NB, 256, 0, stream>>>(dv, cnt);
  k_hist<<<(NE + 255) / 256, 256, 0, stream>>>(ei, ew, dv, cnt);
  k_scan1<<<NB, 256, 0, stream>>>(cnt, off, bsum);
  k_scan2<<<1, 512, 0, stream>>>(bsum);
  k_scan3<<<NB, 256, 0, stream>>>(off, bsum, cur, dv);
  k_place<<<(NE + 255) / 256, 256, 0, stream>>>(ei, ew, dv, cur, elist);

  k_wprep<<<64, 256, 0, stream>>>(W, Wf);
  k_gemm<<<GMB, 256, 0, stream>>>(x, Wf, h);

  k_agg<<<(NN * 32 + 255) / 256, 256, 0, stream>>>(h, dv, cnt, off, elist, x, b, gamma, beta, out);
}